// Round 11
// baseline (212.515 us; speedup 1.0000x reference)
//
#include <hip/hip_runtime.h>
#include <hip/hip_bf16.h>
#include <hip/hip_fp16.h>
#include <cstddef>

// Problem constants
#define NB 2
#define QN 12240
#define SN 12240
#define MREAL 24480          // NB*QN rows
#define MPAD  24576          // 192 * 128
#define MT    192            // M tiles of 128

typedef unsigned short ushortT;
typedef unsigned int uintT;
typedef __bf16 bf16x8 __attribute__((ext_vector_type(8)));
typedef float f32x4 __attribute__((ext_vector_type(4)));
typedef float f32x2 __attribute__((ext_vector_type(2)));

__device__ __forceinline__ ushortT f2bf(float f) {
    uintT u = __float_as_uint(f);
    uintT r = u + 0x7fffu + ((u >> 16) & 1u);   // RNE
    return (ushortT)(r >> 16);
}
__device__ __forceinline__ float bf_lo(uintT u) {   // low bf16 -> f32
    return __uint_as_float(u << 16);
}
__device__ __forceinline__ float bf_hi(uintT u) {   // high bf16 -> f32
    return __uint_as_float(u & 0xffff0000u);
}

__device__ __forceinline__ void async_ld16(const ushortT* g, ushortT* l) {
    __builtin_amdgcn_global_load_lds(
        (const __attribute__((address_space(1))) unsigned int*)g,
        (__attribute__((address_space(3))) unsigned int*)l, 16, 0, 0);
}

// ---------------------------------------------------------------------------
// Weight cast+transpose kernel (q/src casts are fused into gemm_vlo).
// ---------------------------------------------------------------------------
__global__ __launch_bounds__(256) void cast_w(
    const float* __restrict__ Wval, const float* __restrict__ Wattn,
    const float* __restrict__ Woff, const float* __restrict__ Wout,
    ushortT* __restrict__ tval, ushortT* __restrict__ tlo,
    ushortT* __restrict__ tout)
{
    const int bx = blockIdx.x;
    const float* W; ushortT* T; int n, Nw, trow;
    if (bx < 256)      { W = Wval;  T = tval; n = bx;       Nw = 256; trow = n; }
    else if (bx < 384) { W = Wattn; T = tlo;  n = bx - 256; Nw = 128; trow = n; }
    else if (bx < 640) { W = Woff;  T = tlo;  n = bx - 384; Nw = 256; trow = n + 128; }
    else               { W = Wout;  T = tout; n = bx - 640; Nw = 256; trow = n; }
    const int k = threadIdx.x;
    T[(size_t)trow * 256 + k] = f2bf(W[(size_t)k * Nw + n]);
}

// ---------------------------------------------------------------------------
// Fused v + (logits|off) GEMM with fused fp32->bf16 A-cast.
// R11: the R9/R10 regressions were a TLP shortage, not a scheduling
// problem: grid 5x192 = 960 WGs = 3.75 WGs/CU -> Occupancy 17-24% ->
// exposed HBM latency (MfmaUtil 4-6%). Fix: 128x64 output tiles, grid
// 10x192 = 1920 WGs = 7.5 WGs/CU (~30 waves). LDS 12.3 KB, acc[4][2],
// one async B ld_lds per wave. Extra A re-reads are L3-absorbed (R9
// FETCH measured 64 MB vs 250 MB logical). Staging is the simple serial
// form (R10's sched_barrier split regressed and is dropped).
// bx<4: v = src@W_val -> v_bf head-major; bx>=4: lo = q@[W_attn;W_off].
// ---------------------------------------------------------------------------
__global__ __launch_bounds__(256) void gemm_vlo(
    const float* __restrict__ qf, const float* __restrict__ srcf,
    const ushortT* __restrict__ wt_val, const ushortT* __restrict__ wt_lo,
    const float* __restrict__ b_val, const float* __restrict__ b_attn,
    const float* __restrict__ b_off,
    ushortT* __restrict__ v_bf, float* __restrict__ lo_ws)
{
    const int z = blockIdx.x >= 4;
    const int col0 = (z ? blockIdx.x - 4 : blockIdx.x) * 64;

    __shared__ __attribute__((aligned(16))) ushortT As[128 * 32];
    __shared__ __attribute__((aligned(16))) ushortT Bs[64 * 32];

    const float*   Af = z ? qf : srcf;          // fp32 A source (unpadded!)
    const ushortT* Bt = z ? wt_lo : wt_val;

    const int tid  = threadIdx.x;
    const int wave = tid >> 6;
    const int lane = tid & 63;
    const int row0 = blockIdx.y * 128;
    const int wr = (wave >> 1) * 64;    // wave row offset (2 row-groups)
    const int wc = (wave & 1) * 32;     // wave col offset (2 col-groups)

    f32x4 acc[4][2];
    #pragma unroll
    for (int i = 0; i < 4; i++)
        #pragma unroll
        for (int j = 0; j < 2; j++)
            acc[i][j] = (f32x4)0.f;

    const int srow = (lane >> 2);
    const int sk8  = (lane & 3) * 8;
    const int arow = tid >> 3;          // 0..31 (+p*32)
    const int ac4  = (tid & 7) * 4;     // fp32 col quad within 32-k chunk

    // clamped row pointers (OOB rows of the padded last tile clamp to
    // MREAL-1; results discarded by the epilogue row guard)
    const float* ap0 = Af + (size_t)min(row0 +  0 + arow, MREAL - 1) * 256 + ac4;
    const float* ap1 = Af + (size_t)min(row0 + 32 + arow, MREAL - 1) * 256 + ac4;
    const float* ap2 = Af + (size_t)min(row0 + 64 + arow, MREAL - 1) * 256 + ac4;
    const float* ap3 = Af + (size_t)min(row0 + 96 + arow, MREAL - 1) * 256 + ac4;

    for (int k0 = 0; k0 < 256; k0 += 32) {
        // A: fp32 -> bf16 fused cast staging (serial; hidden by ~30
        // waves/CU of TLP, not by intra-wave scheduling)
        #pragma unroll
        for (int p = 0; p < 4; p++) {
            const float* ap = (p == 0) ? ap0 : (p == 1) ? ap1 : (p == 2) ? ap2 : ap3;
            const float4 a4 = *(const float4*)(ap + k0);
            uint2 o;
            o.x = (uintT)f2bf(a4.x) | ((uintT)f2bf(a4.y) << 16);
            o.y = (uintT)f2bf(a4.z) | ((uintT)f2bf(a4.w) << 16);
            *(uint2*)&As[(p * 32 + arow) * 32 + ac4] = o;
        }
        // B: weights (already bf16) via async global->LDS, 16 rows/wave
        async_ld16(Bt + (size_t)(col0 + wave * 16 + srow) * 256 + k0 + sk8,
                   &Bs[(wave * 16) * 32]);
        __syncthreads();

        bf16x8 af[4], bfr[2];
        const int mrow = lane & 15;
        const int kq   = (lane >> 4) * 8;
        #pragma unroll
        for (int i = 0; i < 4; i++)
            af[i]  = *(const bf16x8*)&As[(wr + i * 16 + mrow) * 32 + kq];
        #pragma unroll
        for (int j = 0; j < 2; j++)
            bfr[j] = *(const bf16x8*)&Bs[(wc + j * 16 + mrow) * 32 + kq];
        #pragma unroll
        for (int i = 0; i < 4; i++)
            #pragma unroll
            for (int j = 0; j < 2; j++)
                acc[i][j] = __builtin_amdgcn_mfma_f32_16x16x32_bf16(
                    af[i], bfr[j], acc[i][j], 0, 0, 0);
        __syncthreads();
    }

    const float* bp = z ? ((col0 < 128) ? b_attn : b_off) : b_val;
    const int cofs  = (z && col0 >= 128) ? 128 : 0;

    #pragma unroll
    for (int i = 0; i < 4; i++) {
        const int rbase = row0 + wr + i * 16 + ((lane >> 4) << 2);
        #pragma unroll
        for (int j = 0; j < 2; j++) {
            const int col = col0 + wc + j * 16 + (lane & 15);
            const float bb = bp[col - cofs];
            #pragma unroll
            for (int r = 0; r < 4; r++) {
                const int row = rbase + r;
                if (row < MREAL) {
                    const float val = acc[i][j][r] + bb;
                    if (z) {
                        lo_ws[(size_t)row * 384 + col] = val;
                    } else {
                        // head-major v: (n, head, s, ch); MREAL = 2*SN so
                        // nn is just a compare (no integer divide)
                        const int nn = (row >= SN) ? 1 : 0;
                        const int s  = nn ? (row - SN) : row;
                        const int head = col >> 5, ch = col & 31;
                        v_bf[(((size_t)nn * 8 + head) * SN + s) * 32 + ch] = f2bf(val);
                    }
                }
            }
        }
    }
}

// ---------------------------------------------------------------------------
// Out GEMM (R5 LDS structure): out = mdv(bf16) @ wt_out^T + b_out (fp32).
// ---------------------------------------------------------------------------
__global__ __launch_bounds__(256) void gemm_out(
    const ushortT* __restrict__ A, const ushortT* __restrict__ Bt,
    const float* __restrict__ bias, float* __restrict__ C)
{
    __shared__ __attribute__((aligned(16))) ushortT As[128 * 32];
    __shared__ __attribute__((aligned(16))) ushortT Bs[128 * 32];

    const int tid  = threadIdx.x;
    const int wave = tid >> 6;
    const int lane = tid & 63;
    const int row0 = blockIdx.y * 128;
    const int col0 = blockIdx.x * 128;
    const int wr = (wave >> 1) * 64;
    const int wc = (wave & 1) * 64;

    f32x4 acc[4][4];
    #pragma unroll
    for (int i = 0; i < 4; i++)
        #pragma unroll
        for (int j = 0; j < 4; j++)
            acc[i][j] = (f32x4)0.f;

    const int srow = (lane >> 2);
    const int sk8  = (lane & 3) * 8;

    for (int k0 = 0; k0 < 256; k0 += 32) {
        #pragma unroll
        for (int j = 0; j < 2; j++) {
            const int r = wave * 32 + j * 16;
            async_ld16(A  + (size_t)(row0 + r + srow) * 256 + k0 + sk8, &As[r * 32]);
            async_ld16(Bt + (size_t)(col0 + r + srow) * 256 + k0 + sk8, &Bs[r * 32]);
        }
        __syncthreads();

        bf16x8 af[4], bfr[4];
        const int mrow = lane & 15;
        const int kq   = (lane >> 4) * 8;
        #pragma unroll
        for (int i = 0; i < 4; i++) {
            af[i]  = *(const bf16x8*)&As[(wr + i * 16 + mrow) * 32 + kq];
            bfr[i] = *(const bf16x8*)&Bs[(wc + i * 16 + mrow) * 32 + kq];
        }
        #pragma unroll
        for (int i = 0; i < 4; i++)
            #pragma unroll
            for (int j = 0; j < 4; j++)
                acc[i][j] = __builtin_amdgcn_mfma_f32_16x16x32_bf16(
                    af[i], bfr[j], acc[i][j], 0, 0, 0);
        __syncthreads();
    }

    #pragma unroll
    for (int i = 0; i < 4; i++) {
        const int rbase = row0 + wr + i * 16 + ((lane >> 4) << 2);
        #pragma unroll
        for (int j = 0; j < 4; j++) {
            const int col = col0 + wc + j * 16 + (lane & 15);
            const float bb = bias[col];
            #pragma unroll
            for (int r = 0; r < 4; r++) {
                const int row = rbase + r;
                if (row < MREAL)
                    C[(size_t)row * 256 + col] = acc[i][j][r] + bb;
            }
        }
    }
}

// ---------------------------------------------------------------------------
// Per-head two-phase sample kernel (R8 structure, unchanged: ~46 us,
// bound by ~13 cy/gather-instr at the 32-instr floor + line/VALU floor).
// ---------------------------------------------------------------------------
__global__ __launch_bounds__(256) void sample_kernel(
    const float* __restrict__ lo,       // (N*Q, 384): [0,128) logits, [128,384) off
    const float* __restrict__ geom,     // (N*Q, 4)
    const ushortT* __restrict__ v,      // (N, 8, S, 32) bf16 head-major
    ushortT* __restrict__ out)          // (N*Q, 256) bf16 mdv
{
    const int tid  = threadIdx.x;
    const int w    = tid >> 6;          // wave 0..3
    const int lane = tid & 63;
    const int qi   = lane >> 3;         // query within wave's 8
    const int m    = blockIdx.y;        // head
    const int n    = blockIdx.z;
    int q = blockIdx.x * 32 + w * 8 + qi;
    q = min(q, QN - 1);                 // tail clamp (duplicates are benign)

    // per query: 16 points * 12 ints + 4 pad = 196 ints (stride = 4 banks)
    __shared__ __attribute__((aligned(16))) int pls[4][1568];   // 25088 B

    const size_t qb = (size_t)n * QN + q;

    // ---- phase 1 ----
    {
        const int p = lane & 7;                  // point pair 0..7
        const float* lorow = lo + qb * 384;
        const float2 lg = *(const float2*)(lorow + m * 16 + p * 2);
        const float4 of = *(const float4*)(lorow + 128 + m * 32 + p * 4);
        const float4 g  = *(const float4*)(geom + qb * 4);

        float mx = fmaxf(lg.x, lg.y);
        mx = fmaxf(mx, __shfl_xor(mx, 1));
        mx = fmaxf(mx, __shfl_xor(mx, 2));
        mx = fmaxf(mx, __shfl_xor(mx, 4));
        const float e0 = __expf(lg.x - mx);
        const float e1 = __expf(lg.y - mx);
        float s = e0 + e1;
        s += __shfl_xor(s, 1);
        s += __shfl_xor(s, 2);
        s += __shfl_xor(s, 4);
        const float inv = 1.f / s;

        const int l  = p >> 1;
        const int Wl = 96 >> l;
        const int s0 = (l == 0) ? 0 : (l == 1) ? 9216 : (l == 2) ? 11520 : 12096;
        const float cx = g.x, cy = g.y;
        const float sx = g.z * 0.125f, sy = g.w * 0.125f;
        // record for point pt = t*8 + p lives at qi*196 + pt*12
        int* myrec = &pls[w][qi * 196 + p * 12];

        #pragma unroll
        for (int t = 0; t < 2; t++) {
            const float ox = t ? of.z : of.x;
            const float oy = t ? of.w : of.y;
            const float wa = (t ? e1 : e0) * inv;

            const float x = (cx + ox * sx) * (float)Wl - 0.5f;
            const float y = (cy + oy * sy) * (float)Wl - 0.5f;
            const float xf = floorf(x), yf = floorf(y);
            const int x0 = (int)xf, y0 = (int)yf;
            const float wx = x - xf, wy = y - yf;

            const bool vx0 = (x0 >= 0) & (x0 < Wl);
            const bool vx1 = (x0 + 1 >= 0) & (x0 + 1 < Wl);
            const bool vy0 = (y0 >= 0) & (y0 < Wl);
            const bool vy1 = (y0 + 1 >= 0) & (y0 + 1 < Wl);

            const float w00 = (vx0 & vy0) ? wa * (1.f - wx) * (1.f - wy) : 0.f;
            const float w10 = (vx1 & vy0) ? wa * wx * (1.f - wy) : 0.f;
            const float w01 = (vx0 & vy1) ? wa * (1.f - wx) * wy : 0.f;
            const float w11 = (vx1 & vy1) ? wa * wx * wy : 0.f;

            const int xc0 = min(max(x0, 0), Wl - 1);
            const int xc1 = min(max(x0 + 1, 0), Wl - 1);
            const int yc0 = min(max(y0, 0), Wl - 1);
            const int yc1 = min(max(y0 + 1, 0), Wl - 1);

            const int o00 = (s0 + yc0 * Wl + xc0) << 6;     // byte off, row 64B
            const int dx  = (xc1 - xc0) << 6;               // 0 or 64
            const int dy  = ((yc1 - yc0) * Wl) << 6;        // 0..6144

            // lane cr2=0 handles corners {00 (A), 01 (B)}, cr2=1 {10, 11}
            int4 offs;
            offs.x = o00;            // 00  (A of cr2=0)
            offs.y = o00 + dy;       // 01  (B of cr2=0)
            offs.z = o00 + dx;       // 10  (A of cr2=1)
            offs.w = o00 + dx + dy;  // 11  (B of cr2=1)
            float4 wq0, wq1;
            wq0.x = w00; wq0.y = w00; wq0.z = w01; wq0.w = w01;  // cr2=0 pair
            wq1.x = w10; wq1.y = w10; wq1.z = w11; wq1.w = w11;  // cr2=1 pair

            int* rp = myrec + t * 96;       // pt = t*8 + p
            *(int4*)rp = offs;
            *(float4*)(rp + 4) = wq0;
            *(float4*)(rp + 8) = wq1;
        }
    }
    __syncthreads();

    // ---- phase 2: corner-pair dwordx4 gathers (32 instrs/wave) ----
    const int c   = lane & 7;
    const int c4  = c & 3;              // 16B channel quad (8 channels)
    const int cr2 = c >> 2;             // x-side: 0 -> {00,01}, 1 -> {10,11}
    const unsigned c16 = (unsigned)(c4 * 16);
    const unsigned char* vp = (const unsigned char*)
        (v + ((size_t)(n * 8 + m) * SN) * 32);              // uniform base
    // lane-specialized record base: offsets at +cr2*2, weights at +4+cr2*4
    const int* go = &pls[w][qi * 196] + cr2 * 2;
    const int* gw = &pls[w][qi * 196] + 4 + cr2 * 4;

    // 8 channels per lane: acc0={ch0,1}, acc1={ch2,3}, acc2={ch4,5}, acc3={ch6,7}
    f32x2 acc0 = (f32x2)0.f, acc1 = (f32x2)0.f;
    f32x2 acc2 = (f32x2)0.f, acc3 = (f32x2)0.f;

#define ACC8(U, W) { f32x2 t; \
    t.x = bf_lo((U).x); t.y = bf_hi((U).x); acc0 += (W) * t; \
    t.x = bf_lo((U).y); t.y = bf_hi((U).y); acc1 += (W) * t; \
    t.x = bf_lo((U).z); t.y = bf_hi((U).z); acc2 += (W) * t; \
    t.x = bf_lo((U).w); t.y = bf_hi((U).w); acc3 += (W) * t; }

    #pragma unroll
    for (int g = 0; g < 4; g++) {
        // per-lane offset pairs (b64) for 4 points
        const int2 op0 = *(const int2*)(go + (g * 4 + 0) * 12);
        const int2 op1 = *(const int2*)(go + (g * 4 + 1) * 12);
        const int2 op2 = *(const int2*)(go + (g * 4 + 2) * 12);
        const int2 op3 = *(const int2*)(go + (g * 4 + 3) * 12);

        const uint4 uA0 = *(const uint4*)(vp + ((unsigned)op0.x + c16));
        const uint4 uB0 = *(const uint4*)(vp + ((unsigned)op0.y + c16));
        const uint4 uA1 = *(const uint4*)(vp + ((unsigned)op1.x + c16));
        const uint4 uB1 = *(const uint4*)(vp + ((unsigned)op1.y + c16));
        const uint4 uA2 = *(const uint4*)(vp + ((unsigned)op2.x + c16));
        const uint4 uB2 = *(const uint4*)(vp + ((unsigned)op2.y + c16));
        const uint4 uA3 = *(const uint4*)(vp + ((unsigned)op3.x + c16));
        const uint4 uB3 = *(const uint4*)(vp + ((unsigned)op3.y + c16));

        // per-lane weight quads (b128): (wA,wA,wB,wB)
        const float4 wq0 = *(const float4*)(gw + (g * 4 + 0) * 12);
        const float4 wq1 = *(const float4*)(gw + (g * 4 + 1) * 12);
        const float4 wq2 = *(const float4*)(gw + (g * 4 + 2) * 12);
        const float4 wq3 = *(const float4*)(gw + (g * 4 + 3) * 12);

        f32x2 wv;
        wv.x = wq0.x; wv.y = wq0.y; ACC8(uA0, wv)
        wv.x = wq0.z; wv.y = wq0.w; ACC8(uB0, wv)
        wv.x = wq1.x; wv.y = wq1.y; ACC8(uA1, wv)
        wv.x = wq1.z; wv.y = wq1.w; ACC8(uB1, wv)
        wv.x = wq2.x; wv.y = wq2.y; ACC8(uA2, wv)
        wv.x = wq2.z; wv.y = wq2.w; ACC8(uB2, wv)
        wv.x = wq3.x; wv.y = wq3.y; ACC8(uA3, wv)
        wv.x = wq3.z; wv.y = wq3.w; ACC8(uB3, wv)
    }
#undef ACC8

    // combine corner halves: partner lane (lane ^ 4) holds the other 2 corners
    acc0.x += __shfl_xor(acc0.x, 4); acc0.y += __shfl_xor(acc0.y, 4);
    acc1.x += __shfl_xor(acc1.x, 4); acc1.y += __shfl_xor(acc1.y, 4);
    acc2.x += __shfl_xor(acc2.x, 4); acc2.y += __shfl_xor(acc2.y, 4);
    acc3.x += __shfl_xor(acc3.x, 4); acc3.y += __shfl_xor(acc3.y, 4);

    // lane writes 4 of its 8 channels: cr2=0 -> ch {0..3}, cr2=1 -> ch {4..7}
    const f32x2 wlo = cr2 ? acc2 : acc0;
    const f32x2 whi = cr2 ? acc3 : acc1;
    ushort4 o;
    o.x = f2bf(wlo.x); o.y = f2bf(wlo.y); o.z = f2bf(whi.x); o.w = f2bf(whi.y);
    *(ushort4*)(out + qb * 256 + m * 32 + c4 * 8 + cr2 * 4) = o;
}

// ---------------------------------------------------------------------------
extern "C" void kernel_launch(void* const* d_in, const int* in_sizes, int n_in,
                              void* d_out, int out_size, void* d_ws, size_t ws_size,
                              hipStream_t stream)
{
    const float* queries = (const float*)d_in[0];
    const float* geom    = (const float*)d_in[1];
    const float* src     = (const float*)d_in[2];
    const float* W_off   = (const float*)d_in[3];
    const float* b_off   = (const float*)d_in[4];
    const float* W_attn  = (const float*)d_in[5];
    const float* b_attn  = (const float*)d_in[6];
    const float* W_val   = (const float*)d_in[7];
    const float* b_val   = (const float*)d_in[8];
    const float* W_out   = (const float*)d_in[9];
    const float* b_out   = (const float*)d_in[10];
    float* out = (float*)d_out;

    ushortT* wsb = (ushortT*)d_ws;
    const size_t PADROW = (size_t)MPAD * 256;          // 6,291,456 elems
    ushortT* mdv_bf  = wsb + PADROW;                   // sample output (mdv)
    ushortT* v_bf    = wsb + 2 * PADROW;               // head-major v
    ushortT* wt_val  = wsb + 3 * PADROW;               // 256*256
    ushortT* wt_lo   = wt_val + 65536;                 // 384*256
    ushortT* wt_out  = wt_lo + 98304;                  // 256*256
    float* lo_ws = (float*)(wt_out + 65536);           // 24480*384 fp32

    dim3 blk(256);

    cast_w<<<dim3(896), blk, 0, stream>>>(
        W_val, W_attn, W_off, W_out, wt_val, wt_lo, wt_out);

    // bx<4: v = src@W_val -> v_bf (bf16 head-major); bx>=4: lo -> lo_ws
    // (A read as fp32 directly; cast fused into staging; 64-col tiles
    // for 2x grid parallelism)
    gemm_vlo<<<dim3(10, MT), blk, 0, stream>>>(
        queries, src, wt_val, wt_lo, b_val, b_attn, b_off, v_bf, lo_ws);

    sample_kernel<<<dim3((QN + 31) / 32, 8, NB), dim3(256), 0, stream>>>(
        lo_ws, geom, v_bf, mdv_bf);

    gemm_out<<<dim3(2, MT), blk, 0, stream>>>(mdv_bf, wt_out, b_out, out);
}

// Round 12
// 195.920 us; speedup vs baseline: 1.0847x; 1.0847x over previous
//
#include <hip/hip_runtime.h>
#include <hip/hip_bf16.h>
#include <hip/hip_fp16.h>
#include <cstddef>

// Problem constants
#define NB 2
#define QN 12240
#define SN 12240
#define MREAL 24480          // NB*QN rows
#define MPAD  24576          // 192 * 128
#define MT    192            // M tiles of 128

typedef unsigned short ushortT;
typedef unsigned int uintT;
typedef __bf16 bf16x8 __attribute__((ext_vector_type(8)));
typedef float f32x4 __attribute__((ext_vector_type(4)));
typedef float f32x2 __attribute__((ext_vector_type(2)));

__device__ __forceinline__ ushortT f2bf(float f) {
    uintT u = __float_as_uint(f);
    uintT r = u + 0x7fffu + ((u >> 16) & 1u);   // RNE
    return (ushortT)(r >> 16);
}
__device__ __forceinline__ float bf_lo(uintT u) {   // low bf16 -> f32
    return __uint_as_float(u << 16);
}
__device__ __forceinline__ float bf_hi(uintT u) {   // high bf16 -> f32
    return __uint_as_float(u & 0xffff0000u);
}

__device__ __forceinline__ void async_ld16(const ushortT* g, ushortT* l) {
    __builtin_amdgcn_global_load_lds(
        (const __attribute__((address_space(1))) unsigned int*)g,
        (__attribute__((address_space(3))) unsigned int*)l, 16, 0, 0);
}

// ---------------------------------------------------------------------------
// Merged cast kernel.
// bx in [0,3060): queries -> q_bf (bf16)
// bx in [3060,6120): src -> src_bf
// bx in [6120,7016): weight cast+transpose (W_val/W_attn/W_off/W_out)
// ---------------------------------------------------------------------------
__global__ __launch_bounds__(256) void cast_all(
    const float* __restrict__ q, const float* __restrict__ src,
    const float* __restrict__ Wval, const float* __restrict__ Wattn,
    const float* __restrict__ Woff, const float* __restrict__ Wout,
    ushortT* __restrict__ qb, ushortT* __restrict__ sb,
    ushortT* __restrict__ tval, ushortT* __restrict__ tlo,
    ushortT* __restrict__ tout)
{
    int bx = blockIdx.x;
    if (bx < 6120) {
        const int issrc = bx >= 3060;
        const size_t idx = ((size_t)(bx - (issrc ? 3060 : 0)) * 256 + threadIdx.x) * 8;
        const float* in = issrc ? src : q;
        ushortT* out = issrc ? sb : qb;
        const float4 a = *(const float4*)(in + idx);
        const float4 b = *(const float4*)(in + idx + 4);
        uint4 o;
        o.x = (uintT)f2bf(a.x) | ((uintT)f2bf(a.y) << 16);
        o.y = (uintT)f2bf(a.z) | ((uintT)f2bf(a.w) << 16);
        o.z = (uintT)f2bf(b.x) | ((uintT)f2bf(b.y) << 16);
        o.w = (uintT)f2bf(b.z) | ((uintT)f2bf(b.w) << 16);
        *(uint4*)(out + idx) = o;
        return;
    }
    bx -= 6120;
    const float* W; ushortT* T; int n, Nw, trow;
    if (bx < 256)      { W = Wval;  T = tval; n = bx;       Nw = 256; trow = n; }
    else if (bx < 384) { W = Wattn; T = tlo;  n = bx - 256; Nw = 128; trow = n; }
    else if (bx < 640) { W = Woff;  T = tlo;  n = bx - 384; Nw = 256; trow = n + 128; }
    else               { W = Wout;  T = tout; n = bx - 640; Nw = 256; trow = n; }
    const int k = threadIdx.x;
    T[(size_t)trow * 256 + k] = f2bf(W[(size_t)k * Nw + n]);
}

// ---------------------------------------------------------------------------
// Fused v + (logits|off) GEMM, LDS-staged (R5 structure), flat grid.
// ---------------------------------------------------------------------------
__global__ __launch_bounds__(256) void gemm_vlo(
    const ushortT* __restrict__ q_bf, const ushortT* __restrict__ src_bf,
    const ushortT* __restrict__ wt_val, const ushortT* __restrict__ wt_lo,
    const float* __restrict__ b_val, const float* __restrict__ b_attn,
    const float* __restrict__ b_off,
    ushortT* __restrict__ v_bf, float* __restrict__ lo_ws)
{
    const int z = blockIdx.x >= 2;
    const int col0 = (z ? blockIdx.x - 2 : blockIdx.x) * 128;

    __shared__ __attribute__((aligned(16))) ushortT As[128 * 32];
    __shared__ __attribute__((aligned(16))) ushortT Bs[128 * 32];

    const ushortT* A  = z ? q_bf : src_bf;
    const ushortT* Bt = z ? wt_lo : wt_val;

    const int tid  = threadIdx.x;
    const int wave = tid >> 6;
    const int lane = tid & 63;
    const int row0 = blockIdx.y * 128;
    const int wr = (wave >> 1) * 64;
    const int wc = (wave & 1) * 64;

    f32x4 acc[4][4];
    #pragma unroll
    for (int i = 0; i < 4; i++)
        #pragma unroll
        for (int j = 0; j < 4; j++)
            acc[i][j] = (f32x4)0.f;

    const int srow = (lane >> 2);
    const int sk8  = (lane & 3) * 8;

    for (int k0 = 0; k0 < 256; k0 += 32) {
        #pragma unroll
        for (int j = 0; j < 2; j++) {
            const int r = wave * 32 + j * 16;
            async_ld16(A  + (size_t)(row0 + r + srow) * 256 + k0 + sk8, &As[r * 32]);
            async_ld16(Bt + (size_t)(col0 + r + srow) * 256 + k0 + sk8, &Bs[r * 32]);
        }
        __syncthreads();

        bf16x8 af[4], bfr[4];
        const int mrow = lane & 15;
        const int kq   = (lane >> 4) * 8;
        #pragma unroll
        for (int i = 0; i < 4; i++) {
            af[i]  = *(const bf16x8*)&As[(wr + i * 16 + mrow) * 32 + kq];
            bfr[i] = *(const bf16x8*)&Bs[(wc + i * 16 + mrow) * 32 + kq];
        }
        #pragma unroll
        for (int i = 0; i < 4; i++)
            #pragma unroll
            for (int j = 0; j < 4; j++)
                acc[i][j] = __builtin_amdgcn_mfma_f32_16x16x32_bf16(
                    af[i], bfr[j], acc[i][j], 0, 0, 0);
        __syncthreads();
    }

    const float* bp = z ? ((col0 < 128) ? b_attn : b_off) : b_val;
    const int cofs  = (z && col0 >= 128) ? 128 : 0;

    #pragma unroll
    for (int i = 0; i < 4; i++) {
        const int rbase = row0 + wr + i * 16 + ((lane >> 4) << 2);
        #pragma unroll
        for (int j = 0; j < 4; j++) {
            const int col = col0 + wc + j * 16 + (lane & 15);
            const float bb = bp[col - cofs];
            #pragma unroll
            for (int r = 0; r < 4; r++) {
                const int row = rbase + r;
                if (row < MREAL) {
                    const float val = acc[i][j][r] + bb;
                    if (z) {
                        lo_ws[(size_t)row * 384 + col] = val;
                    } else {
                        // head-major v: (n, head, s, ch); MREAL = 2*SN so
                        // nn is just a compare (no integer divide)
                        const int nn = (row >= SN) ? 1 : 0;
                        const int s  = nn ? (row - SN) : row;
                        const int head = col >> 5, ch = col & 31;
                        v_bf[(((size_t)nn * 8 + head) * SN + s) * 32 + ch] = f2bf(val);
                    }
                }
            }
        }
    }
}

// ---------------------------------------------------------------------------
// Out GEMM (R5 LDS structure): out = mdv(bf16) @ wt_out^T + b_out (fp32).
// ---------------------------------------------------------------------------
__global__ __launch_bounds__(256) void gemm_out(
    const ushortT* __restrict__ A, const ushortT* __restrict__ Bt,
    const float* __restrict__ bias, float* __restrict__ C)
{
    __shared__ __attribute__((aligned(16))) ushortT As[128 * 32];
    __shared__ __attribute__((aligned(16))) ushortT Bs[128 * 32];

    const int tid  = threadIdx.x;
    const int wave = tid >> 6;
    const int lane = tid & 63;
    const int row0 = blockIdx.y * 128;
    const int col0 = blockIdx.x * 128;
    const int wr = (wave >> 1) * 64;
    const int wc = (wave & 1) * 64;

    f32x4 acc[4][4];
    #pragma unroll
    for (int i = 0; i < 4; i++)
        #pragma unroll
        for (int j = 0; j < 4; j++)
            acc[i][j] = (f32x4)0.f;

    const int srow = (lane >> 2);
    const int sk8  = (lane & 3) * 8;

    for (int k0 = 0; k0 < 256; k0 += 32) {
        #pragma unroll
        for (int j = 0; j < 2; j++) {
            const int r = wave * 32 + j * 16;
            async_ld16(A  + (size_t)(row0 + r + srow) * 256 + k0 + sk8, &As[r * 32]);
            async_ld16(Bt + (size_t)(col0 + r + srow) * 256 + k0 + sk8, &Bs[r * 32]);
        }
        __syncthreads();

        bf16x8 af[4], bfr[4];
        const int mrow = lane & 15;
        const int kq   = (lane >> 4) * 8;
        #pragma unroll
        for (int i = 0; i < 4; i++) {
            af[i]  = *(const bf16x8*)&As[(wr + i * 16 + mrow) * 32 + kq];
            bfr[i] = *(const bf16x8*)&Bs[(wc + i * 16 + mrow) * 32 + kq];
        }
        #pragma unroll
        for (int i = 0; i < 4; i++)
            #pragma unroll
            for (int j = 0; j < 4; j++)
                acc[i][j] = __builtin_amdgcn_mfma_f32_16x16x32_bf16(
                    af[i], bfr[j], acc[i][j], 0, 0, 0);
        __syncthreads();
    }

    #pragma unroll
    for (int i = 0; i < 4; i++) {
        const int rbase = row0 + wr + i * 16 + ((lane >> 4) << 2);
        #pragma unroll
        for (int j = 0; j < 4; j++) {
            const int col = col0 + wc + j * 16 + (lane & 15);
            const float bb = bias[col];
            #pragma unroll
            for (int r = 0; r < 4; r++) {
                const int row = rbase + r;
                if (row < MREAL)
                    C[(size_t)row * 256 + col] = acc[i][j][r] + bb;
            }
        }
    }
}

// ---------------------------------------------------------------------------
// Per-head two-phase sample kernel. Block = 256 threads = 4 waves =
// 32 queries of ONE head (grid: 383 x 8 x 2; tail clamps q, duplicate
// writes of identical values are benign).
// R7-proven form (194.7 us total, sample ~46.5 us, bank conflicts 0):
// corner-pair dwordx4 gathers, 32 gather instrs/wave (the VMEM
// instruction-processing floor for bf16: ~13 cy/instr + line/VALU floor).
// ---------------------------------------------------------------------------
__global__ __launch_bounds__(256) void sample_kernel(
    const float* __restrict__ lo,       // (N*Q, 384): [0,128) logits, [128,384) off
    const float* __restrict__ geom,     // (N*Q, 4)
    const ushortT* __restrict__ v,      // (N, 8, S, 32) bf16 head-major
    ushortT* __restrict__ out)          // (N*Q, 256) bf16 mdv
{
    const int tid  = threadIdx.x;
    const int w    = tid >> 6;          // wave 0..3
    const int lane = tid & 63;
    const int qi   = lane >> 3;         // query within wave's 8
    const int m    = blockIdx.y;        // head
    const int n    = blockIdx.z;
    int q = blockIdx.x * 32 + w * 8 + qi;
    q = min(q, QN - 1);                 // tail clamp (duplicates are benign)

    // per query: 16 points * 12 ints + 4 pad = 196 ints (stride = 4 banks)
    __shared__ __attribute__((aligned(16))) int pls[4][1568];   // 25088 B

    const size_t qb = (size_t)n * QN + q;

    // ---- phase 1 ----
    {
        const int p = lane & 7;                  // point pair 0..7
        const float* lorow = lo + qb * 384;
        const float2 lg = *(const float2*)(lorow + m * 16 + p * 2);
        const float4 of = *(const float4*)(lorow + 128 + m * 32 + p * 4);
        const float4 g  = *(const float4*)(geom + qb * 4);

        float mx = fmaxf(lg.x, lg.y);
        mx = fmaxf(mx, __shfl_xor(mx, 1));
        mx = fmaxf(mx, __shfl_xor(mx, 2));
        mx = fmaxf(mx, __shfl_xor(mx, 4));
        const float e0 = __expf(lg.x - mx);
        const float e1 = __expf(lg.y - mx);
        float s = e0 + e1;
        s += __shfl_xor(s, 1);
        s += __shfl_xor(s, 2);
        s += __shfl_xor(s, 4);
        const float inv = 1.f / s;

        const int l  = p >> 1;
        const int Wl = 96 >> l;
        const int s0 = (l == 0) ? 0 : (l == 1) ? 9216 : (l == 2) ? 11520 : 12096;
        const float cx = g.x, cy = g.y;
        const float sx = g.z * 0.125f, sy = g.w * 0.125f;
        // record for point pt = t*8 + p lives at qi*196 + pt*12
        int* myrec = &pls[w][qi * 196 + p * 12];

        #pragma unroll
        for (int t = 0; t < 2; t++) {
            const float ox = t ? of.z : of.x;
            const float oy = t ? of.w : of.y;
            const float wa = (t ? e1 : e0) * inv;

            const float x = (cx + ox * sx) * (float)Wl - 0.5f;
            const float y = (cy + oy * sy) * (float)Wl - 0.5f;
            const float xf = floorf(x), yf = floorf(y);
            const int x0 = (int)xf, y0 = (int)yf;
            const float wx = x - xf, wy = y - yf;

            const bool vx0 = (x0 >= 0) & (x0 < Wl);
            const bool vx1 = (x0 + 1 >= 0) & (x0 + 1 < Wl);
            const bool vy0 = (y0 >= 0) & (y0 < Wl);
            const bool vy1 = (y0 + 1 >= 0) & (y0 + 1 < Wl);

            const float w00 = (vx0 & vy0) ? wa * (1.f - wx) * (1.f - wy) : 0.f;
            const float w10 = (vx1 & vy0) ? wa * wx * (1.f - wy) : 0.f;
            const float w01 = (vx0 & vy1) ? wa * (1.f - wx) * wy : 0.f;
            const float w11 = (vx1 & vy1) ? wa * wx * wy : 0.f;

            const int xc0 = min(max(x0, 0), Wl - 1);
            const int xc1 = min(max(x0 + 1, 0), Wl - 1);
            const int yc0 = min(max(y0, 0), Wl - 1);
            const int yc1 = min(max(y0 + 1, 0), Wl - 1);

            const int o00 = (s0 + yc0 * Wl + xc0) << 6;     // byte off, row 64B
            const int dx  = (xc1 - xc0) << 6;               // 0 or 64
            const int dy  = ((yc1 - yc0) * Wl) << 6;        // 0..6144

            int4 offs;
            offs.x = o00;           // corner 00 -> weight at rp+4
            offs.y = o00 + dx;      // corner 10 -> weight at rp+6
            offs.z = o00 + dy;      // corner 01 -> weight at rp+8
            offs.w = o00 + dy + dx; // corner 11 -> weight at rp+10
            float4 wab, wcd;
            wab.x = w00; wab.y = w00; wab.z = w10; wab.w = w10;
            wcd.x = w01; wcd.y = w01; wcd.z = w11; wcd.w = w11;

            int* rp = myrec + t * 96;       // pt = t*8 + p
            *(int4*)rp = offs;
            *(float4*)(rp + 4) = wab;
            *(float4*)(rp + 8) = wcd;
        }
    }
    __syncthreads();

    // ---- phase 2: corner-pair dwordx4 gathers (32 instrs/wave) ----
    const int c   = lane & 7;
    const int c4  = c & 3;              // 16B channel quad (8 channels)
    const int cr2 = c >> 2;             // corner of pair: A={00,10}, B={01,11}
    const unsigned c16 = (unsigned)(c4 * 16);
    const unsigned char* vp = (const unsigned char*)
        (v + ((size_t)(n * 8 + m) * SN) * 32);              // uniform base
    const int* grec = &pls[w][qi * 196];
    const int* gw   = grec + 4 + cr2 * 2;   // per-lane weight base

    // 8 channels per lane: acc0={ch0,1}, acc1={ch2,3}, acc2={ch4,5}, acc3={ch6,7}
    f32x2 acc0 = (f32x2)0.f, acc1 = (f32x2)0.f;
    f32x2 acc2 = (f32x2)0.f, acc3 = (f32x2)0.f;

#define ACC8(U, W) { f32x2 t; \
    t.x = bf_lo((U).x); t.y = bf_hi((U).x); acc0 += (W) * t; \
    t.x = bf_lo((U).y); t.y = bf_hi((U).y); acc1 += (W) * t; \
    t.x = bf_lo((U).z); t.y = bf_hi((U).z); acc2 += (W) * t; \
    t.x = bf_lo((U).w); t.y = bf_hi((U).w); acc3 += (W) * t; }

    #pragma unroll
    for (int g = 0; g < 4; g++) {
        const int4 o0 = *(const int4*)(grec + (g * 4 + 0) * 12);
        const int4 o1 = *(const int4*)(grec + (g * 4 + 1) * 12);
        const int4 o2 = *(const int4*)(grec + (g * 4 + 2) * 12);
        const int4 o3 = *(const int4*)(grec + (g * 4 + 3) * 12);

        // per point: corner cr2 (A) and corner 2+cr2 (B), 16B each
        const unsigned a0 = (unsigned)(cr2 ? o0.y : o0.x) + c16;
        const unsigned b0 = (unsigned)(cr2 ? o0.w : o0.z) + c16;
        const unsigned a1 = (unsigned)(cr2 ? o1.y : o1.x) + c16;
        const unsigned b1 = (unsigned)(cr2 ? o1.w : o1.z) + c16;
        const unsigned a2 = (unsigned)(cr2 ? o2.y : o2.x) + c16;
        const unsigned b2 = (unsigned)(cr2 ? o2.w : o2.z) + c16;
        const unsigned a3 = (unsigned)(cr2 ? o3.y : o3.x) + c16;
        const unsigned b3 = (unsigned)(cr2 ? o3.w : o3.z) + c16;

        const uint4 uA0 = *(const uint4*)(vp + a0);
        const uint4 uB0 = *(const uint4*)(vp + b0);
        const uint4 uA1 = *(const uint4*)(vp + a1);
        const uint4 uB1 = *(const uint4*)(vp + b1);
        const uint4 uA2 = *(const uint4*)(vp + a2);
        const uint4 uB2 = *(const uint4*)(vp + b2);
        const uint4 uA3 = *(const uint4*)(vp + a3);
        const uint4 uB3 = *(const uint4*)(vp + b3);

        const f32x2 wA0 = *(const f32x2*)(gw + (g * 4 + 0) * 12);
        const f32x2 wB0 = *(const f32x2*)(gw + (g * 4 + 0) * 12 + 4);
        const f32x2 wA1 = *(const f32x2*)(gw + (g * 4 + 1) * 12);
        const f32x2 wB1 = *(const f32x2*)(gw + (g * 4 + 1) * 12 + 4);
        const f32x2 wA2 = *(const f32x2*)(gw + (g * 4 + 2) * 12);
        const f32x2 wB2 = *(const f32x2*)(gw + (g * 4 + 2) * 12 + 4);
        const f32x2 wA3 = *(const f32x2*)(gw + (g * 4 + 3) * 12);
        const f32x2 wB3 = *(const f32x2*)(gw + (g * 4 + 3) * 12 + 4);

        ACC8(uA0, wA0) ACC8(uB0, wB0)
        ACC8(uA1, wA1) ACC8(uB1, wB1)
        ACC8(uA2, wA2) ACC8(uB2, wB2)
        ACC8(uA3, wA3) ACC8(uB3, wB3)
    }
#undef ACC8

    // combine corner halves: partner lane (lane ^ 4) holds the other 2 corners
    acc0.x += __shfl_xor(acc0.x, 4); acc0.y += __shfl_xor(acc0.y, 4);
    acc1.x += __shfl_xor(acc1.x, 4); acc1.y += __shfl_xor(acc1.y, 4);
    acc2.x += __shfl_xor(acc2.x, 4); acc2.y += __shfl_xor(acc2.y, 4);
    acc3.x += __shfl_xor(acc3.x, 4); acc3.y += __shfl_xor(acc3.y, 4);

    // lane writes 4 of its 8 channels: cr2=0 -> ch {0..3}, cr2=1 -> ch {4..7}
    const f32x2 wlo = cr2 ? acc2 : acc0;
    const f32x2 whi = cr2 ? acc3 : acc1;
    ushort4 o;
    o.x = f2bf(wlo.x); o.y = f2bf(wlo.y); o.z = f2bf(whi.x); o.w = f2bf(whi.y);
    *(ushort4*)(out + qb * 256 + m * 32 + c4 * 8 + cr2 * 4) = o;
}

// ---------------------------------------------------------------------------
extern "C" void kernel_launch(void* const* d_in, const int* in_sizes, int n_in,
                              void* d_out, int out_size, void* d_ws, size_t ws_size,
                              hipStream_t stream)
{
    const float* queries = (const float*)d_in[0];
    const float* geom    = (const float*)d_in[1];
    const float* src     = (const float*)d_in[2];
    const float* W_off   = (const float*)d_in[3];
    const float* b_off   = (const float*)d_in[4];
    const float* W_attn  = (const float*)d_in[5];
    const float* b_attn  = (const float*)d_in[6];
    const float* W_val   = (const float*)d_in[7];
    const float* b_val   = (const float*)d_in[8];
    const float* W_out   = (const float*)d_in[9];
    const float* b_out   = (const float*)d_in[10];
    float* out = (float*)d_out;

    ushortT* wsb = (ushortT*)d_ws;
    const size_t PADROW = (size_t)MPAD * 256;          // 6,291,456 elems
    ushortT* q_bf    = wsb;
    ushortT* srcmdv  = wsb + PADROW;                   // src_bf, later mdv_bf
    ushortT* v_bf    = wsb + 2 * PADROW;               // head-major v
    ushortT* wt_val  = wsb + 3 * PADROW;               // 256*256
    ushortT* wt_lo   = wt_val + 65536;                 // 384*256
    ushortT* wt_out  = wt_lo + 98304;                  // 256*256
    float* lo_ws = (float*)(wt_out + 65536);           // 24480*384 fp32
    // total ~75.8 MB

    dim3 blk(256);

    cast_all<<<dim3(7016), blk, 0, stream>>>(
        queries, src, W_val, W_attn, W_off, W_out,
        q_bf, srcmdv, wt_val, wt_lo, wt_out);

    // bx<2: v = src@W_val -> v_bf (bf16 head-major); bx>=2: lo -> lo_ws
    gemm_vlo<<<dim3(5, MT), blk, 0, stream>>>(
        q_bf, srcmdv, wt_val, wt_lo, b_val, b_attn, b_off, v_bf, lo_ws);

    sample_kernel<<<dim3((QN + 31) / 32, 8, NB), dim3(256), 0, stream>>>(
        lo_ws, geom, v_bf, srcmdv);

    gemm_out<<<dim3(2, MT), blk, 0, stream>>>(srcmdv, wt_out, b_out, out);
}

// Round 13
// 193.384 us; speedup vs baseline: 1.0989x; 1.0131x over previous
//
#include <hip/hip_runtime.h>
#include <hip/hip_bf16.h>
#include <hip/hip_fp16.h>
#include <cstddef>

// Problem constants
#define NB 2
#define QN 12240
#define SN 12240
#define MREAL 24480          // NB*QN rows
#define MPAD  24576          // 192 * 128
#define MT    192            // M tiles of 128

typedef unsigned short ushortT;
typedef unsigned int uintT;
typedef __bf16 bf16x8 __attribute__((ext_vector_type(8)));
typedef float f32x4 __attribute__((ext_vector_type(4)));
typedef float f32x2 __attribute__((ext_vector_type(2)));

__device__ __forceinline__ ushortT f2bf(float f) {
    uintT u = __float_as_uint(f);
    uintT r = u + 0x7fffu + ((u >> 16) & 1u);   // RNE
    return (ushortT)(r >> 16);
}
__device__ __forceinline__ float bf_lo(uintT u) {   // low bf16 -> f32
    return __uint_as_float(u << 16);
}
__device__ __forceinline__ float bf_hi(uintT u) {   // high bf16 -> f32
    return __uint_as_float(u & 0xffff0000u);
}

__device__ __forceinline__ void async_ld16(const ushortT* g, ushortT* l) {
    __builtin_amdgcn_global_load_lds(
        (const __attribute__((address_space(1))) unsigned int*)g,
        (__attribute__((address_space(3))) unsigned int*)l, 16, 0, 0);
}

// ---------------------------------------------------------------------------
// Merged cast kernel.
// bx in [0,3060): queries -> q_bf (bf16)
// bx in [3060,6120): src -> src_bf
// bx in [6120,7016): weight cast+transpose (W_val/W_attn/W_off/W_out)
// ---------------------------------------------------------------------------
__global__ __launch_bounds__(256) void cast_all(
    const float* __restrict__ q, const float* __restrict__ src,
    const float* __restrict__ Wval, const float* __restrict__ Wattn,
    const float* __restrict__ Woff, const float* __restrict__ Wout,
    ushortT* __restrict__ qb, ushortT* __restrict__ sb,
    ushortT* __restrict__ tval, ushortT* __restrict__ tlo,
    ushortT* __restrict__ tout)
{
    int bx = blockIdx.x;
    if (bx < 6120) {
        const int issrc = bx >= 3060;
        const size_t idx = ((size_t)(bx - (issrc ? 3060 : 0)) * 256 + threadIdx.x) * 8;
        const float* in = issrc ? src : q;
        ushortT* out = issrc ? sb : qb;
        const float4 a = *(const float4*)(in + idx);
        const float4 b = *(const float4*)(in + idx + 4);
        uint4 o;
        o.x = (uintT)f2bf(a.x) | ((uintT)f2bf(a.y) << 16);
        o.y = (uintT)f2bf(a.z) | ((uintT)f2bf(a.w) << 16);
        o.z = (uintT)f2bf(b.x) | ((uintT)f2bf(b.y) << 16);
        o.w = (uintT)f2bf(b.z) | ((uintT)f2bf(b.w) << 16);
        *(uint4*)(out + idx) = o;
        return;
    }
    bx -= 6120;
    const float* W; ushortT* T; int n, Nw, trow;
    if (bx < 256)      { W = Wval;  T = tval; n = bx;       Nw = 256; trow = n; }
    else if (bx < 384) { W = Wattn; T = tlo;  n = bx - 256; Nw = 128; trow = n; }
    else if (bx < 640) { W = Woff;  T = tlo;  n = bx - 384; Nw = 256; trow = n + 128; }
    else               { W = Wout;  T = tout; n = bx - 640; Nw = 256; trow = n; }
    const int k = threadIdx.x;
    T[(size_t)trow * 256 + k] = f2bf(W[(size_t)k * Nw + n]);
}

// ---------------------------------------------------------------------------
// Fused v + (logits|off) GEMM. R13: 64x128 output tiles, grid (5, 384)
// = 1920 WGs = 7.5 WGs/CU. R9's direct measurement showed the 5x192
// (128-row-tile) geometry runs at Occupancy 17-24% -> latency-exposed
// K-loop. M-split adds TLP without changing A-refetch (same rows, same
// column blocks; A is bf16 + L3-resident, unlike R11's fp32-refetch
// poison); B-staging doubles but weights are L2-resident (<200 KB).
// bx<2: v = src@W_val -> v_bf head-major; bx>=2: lo = q@[W_attn;W_off].
// ---------------------------------------------------------------------------
__global__ __launch_bounds__(256) void gemm_vlo(
    const ushortT* __restrict__ q_bf, const ushortT* __restrict__ src_bf,
    const ushortT* __restrict__ wt_val, const ushortT* __restrict__ wt_lo,
    const float* __restrict__ b_val, const float* __restrict__ b_attn,
    const float* __restrict__ b_off,
    ushortT* __restrict__ v_bf, float* __restrict__ lo_ws)
{
    const int z = blockIdx.x >= 2;
    const int col0 = (z ? blockIdx.x - 2 : blockIdx.x) * 128;

    __shared__ __attribute__((aligned(16))) ushortT As[64 * 32];
    __shared__ __attribute__((aligned(16))) ushortT Bs[128 * 32];

    const ushortT* A  = z ? q_bf : src_bf;
    const ushortT* Bt = z ? wt_lo : wt_val;

    const int tid  = threadIdx.x;
    const int wave = tid >> 6;
    const int lane = tid & 63;
    const int row0 = blockIdx.y * 64;
    const int wr = (wave >> 1) * 32;    // 2 row-groups of 32
    const int wc = (wave & 1) * 64;     // 2 col-groups of 64

    f32x4 acc[2][4];
    #pragma unroll
    for (int i = 0; i < 2; i++)
        #pragma unroll
        for (int j = 0; j < 4; j++)
            acc[i][j] = (f32x4)0.f;

    const int srow = (lane >> 2);
    const int sk8  = (lane & 3) * 8;

    for (int k0 = 0; k0 < 256; k0 += 32) {
        // A: 64 rows, 16 per wave
        async_ld16(A + (size_t)(row0 + wave * 16 + srow) * 256 + k0 + sk8,
                   &As[(wave * 16) * 32]);
        // B: 128 rows, 32 per wave
        #pragma unroll
        for (int j = 0; j < 2; j++) {
            const int r = wave * 32 + j * 16;
            async_ld16(Bt + (size_t)(col0 + r + srow) * 256 + k0 + sk8, &Bs[r * 32]);
        }
        __syncthreads();

        bf16x8 af[2], bfr[4];
        const int mrow = lane & 15;
        const int kq   = (lane >> 4) * 8;
        #pragma unroll
        for (int i = 0; i < 2; i++)
            af[i]  = *(const bf16x8*)&As[(wr + i * 16 + mrow) * 32 + kq];
        #pragma unroll
        for (int j = 0; j < 4; j++)
            bfr[j] = *(const bf16x8*)&Bs[(wc + j * 16 + mrow) * 32 + kq];
        #pragma unroll
        for (int i = 0; i < 2; i++)
            #pragma unroll
            for (int j = 0; j < 4; j++)
                acc[i][j] = __builtin_amdgcn_mfma_f32_16x16x32_bf16(
                    af[i], bfr[j], acc[i][j], 0, 0, 0);
        __syncthreads();
    }

    const float* bp = z ? ((col0 < 128) ? b_attn : b_off) : b_val;
    const int cofs  = (z && col0 >= 128) ? 128 : 0;

    #pragma unroll
    for (int i = 0; i < 2; i++) {
        const int rbase = row0 + wr + i * 16 + ((lane >> 4) << 2);
        #pragma unroll
        for (int j = 0; j < 4; j++) {
            const int col = col0 + wc + j * 16 + (lane & 15);
            const float bb = bp[col - cofs];
            #pragma unroll
            for (int r = 0; r < 4; r++) {
                const int row = rbase + r;
                if (row < MREAL) {
                    const float val = acc[i][j][r] + bb;
                    if (z) {
                        lo_ws[(size_t)row * 384 + col] = val;
                    } else {
                        // head-major v: (n, head, s, ch); MREAL = 2*SN so
                        // nn is just a compare (no integer divide)
                        const int nn = (row >= SN) ? 1 : 0;
                        const int s  = nn ? (row - SN) : row;
                        const int head = col >> 5, ch = col & 31;
                        v_bf[(((size_t)nn * 8 + head) * SN + s) * 32 + ch] = f2bf(val);
                    }
                }
            }
        }
    }
}

// ---------------------------------------------------------------------------
// Out GEMM. R13: 64x64 tiles, grid (4, 384) = 1536 WGs = 6 WGs/CU
// (was 2x192 = 384 WGs = 1.5 WGs/CU -- over half the CUs idle).
// out = mdv(bf16) @ wt_out^T + b_out (fp32).
// ---------------------------------------------------------------------------
__global__ __launch_bounds__(256) void gemm_out(
    const ushortT* __restrict__ A, const ushortT* __restrict__ Bt,
    const float* __restrict__ bias, float* __restrict__ C)
{
    __shared__ __attribute__((aligned(16))) ushortT As[64 * 32];
    __shared__ __attribute__((aligned(16))) ushortT Bs[64 * 32];

    const int tid  = threadIdx.x;
    const int wave = tid >> 6;
    const int lane = tid & 63;
    const int row0 = blockIdx.y * 64;
    const int col0 = blockIdx.x * 64;
    const int wr = (wave >> 1) * 32;
    const int wc = (wave & 1) * 32;

    f32x4 acc[2][2];
    #pragma unroll
    for (int i = 0; i < 2; i++)
        #pragma unroll
        for (int j = 0; j < 2; j++)
            acc[i][j] = (f32x4)0.f;

    const int srow = (lane >> 2);
    const int sk8  = (lane & 3) * 8;

    for (int k0 = 0; k0 < 256; k0 += 32) {
        // A and B: 64 rows each, 16 per wave
        async_ld16(A  + (size_t)(row0 + wave * 16 + srow) * 256 + k0 + sk8,
                   &As[(wave * 16) * 32]);
        async_ld16(Bt + (size_t)(col0 + wave * 16 + srow) * 256 + k0 + sk8,
                   &Bs[(wave * 16) * 32]);
        __syncthreads();

        bf16x8 af[2], bfr[2];
        const int mrow = lane & 15;
        const int kq   = (lane >> 4) * 8;
        #pragma unroll
        for (int i = 0; i < 2; i++) {
            af[i]  = *(const bf16x8*)&As[(wr + i * 16 + mrow) * 32 + kq];
            bfr[i] = *(const bf16x8*)&Bs[(wc + i * 16 + mrow) * 32 + kq];
        }
        #pragma unroll
        for (int i = 0; i < 2; i++)
            #pragma unroll
            for (int j = 0; j < 2; j++)
                acc[i][j] = __builtin_amdgcn_mfma_f32_16x16x32_bf16(
                    af[i], bfr[j], acc[i][j], 0, 0, 0);
        __syncthreads();
    }

    #pragma unroll
    for (int i = 0; i < 2; i++) {
        const int rbase = row0 + wr + i * 16 + ((lane >> 4) << 2);
        #pragma unroll
        for (int j = 0; j < 2; j++) {
            const int col = col0 + wc + j * 16 + (lane & 15);
            const float bb = bias[col];
            #pragma unroll
            for (int r = 0; r < 4; r++) {
                const int row = rbase + r;
                if (row < MREAL)
                    C[(size_t)row * 256 + col] = acc[i][j][r] + bb;
            }
        }
    }
}

// ---------------------------------------------------------------------------
// Per-head two-phase sample kernel. Block = 256 threads = 4 waves =
// 32 queries of ONE head (grid: 383 x 8 x 2; tail clamps q, duplicate
// writes of identical values are benign).
// R7-proven form (194.7 us total, sample ~46.5 us, bank conflicts 0):
// corner-pair dwordx4 gathers, 32 gather instrs/wave (the VMEM
// instruction-processing floor for bf16: ~13 cy/instr + line/VALU floor).
// ---------------------------------------------------------------------------
__global__ __launch_bounds__(256) void sample_kernel(
    const float* __restrict__ lo,       // (N*Q, 384): [0,128) logits, [128,384) off
    const float* __restrict__ geom,     // (N*Q, 4)
    const ushortT* __restrict__ v,      // (N, 8, S, 32) bf16 head-major
    ushortT* __restrict__ out)          // (N*Q, 256) bf16 mdv
{
    const int tid  = threadIdx.x;
    const int w    = tid >> 6;          // wave 0..3
    const int lane = tid & 63;
    const int qi   = lane >> 3;         // query within wave's 8
    const int m    = blockIdx.y;        // head
    const int n    = blockIdx.z;
    int q = blockIdx.x * 32 + w * 8 + qi;
    q = min(q, QN - 1);                 // tail clamp (duplicates are benign)

    // per query: 16 points * 12 ints + 4 pad = 196 ints (stride = 4 banks)
    __shared__ __attribute__((aligned(16))) int pls[4][1568];   // 25088 B

    const size_t qb = (size_t)n * QN + q;

    // ---- phase 1 ----
    {
        const int p = lane & 7;                  // point pair 0..7
        const float* lorow = lo + qb * 384;
        const float2 lg = *(const float2*)(lorow + m * 16 + p * 2);
        const float4 of = *(const float4*)(lorow + 128 + m * 32 + p * 4);
        const float4 g  = *(const float4*)(geom + qb * 4);

        float mx = fmaxf(lg.x, lg.y);
        mx = fmaxf(mx, __shfl_xor(mx, 1));
        mx = fmaxf(mx, __shfl_xor(mx, 2));
        mx = fmaxf(mx, __shfl_xor(mx, 4));
        const float e0 = __expf(lg.x - mx);
        const float e1 = __expf(lg.y - mx);
        float s = e0 + e1;
        s += __shfl_xor(s, 1);
        s += __shfl_xor(s, 2);
        s += __shfl_xor(s, 4);
        const float inv = 1.f / s;

        const int l  = p >> 1;
        const int Wl = 96 >> l;
        const int s0 = (l == 0) ? 0 : (l == 1) ? 9216 : (l == 2) ? 11520 : 12096;
        const float cx = g.x, cy = g.y;
        const float sx = g.z * 0.125f, sy = g.w * 0.125f;
        // record for point pt = t*8 + p lives at qi*196 + pt*12
        int* myrec = &pls[w][qi * 196 + p * 12];

        #pragma unroll
        for (int t = 0; t < 2; t++) {
            const float ox = t ? of.z : of.x;
            const float oy = t ? of.w : of.y;
            const float wa = (t ? e1 : e0) * inv;

            const float x = (cx + ox * sx) * (float)Wl - 0.5f;
            const float y = (cy + oy * sy) * (float)Wl - 0.5f;
            const float xf = floorf(x), yf = floorf(y);
            const int x0 = (int)xf, y0 = (int)yf;
            const float wx = x - xf, wy = y - yf;

            const bool vx0 = (x0 >= 0) & (x0 < Wl);
            const bool vx1 = (x0 + 1 >= 0) & (x0 + 1 < Wl);
            const bool vy0 = (y0 >= 0) & (y0 < Wl);
            const bool vy1 = (y0 + 1 >= 0) & (y0 + 1 < Wl);

            const float w00 = (vx0 & vy0) ? wa * (1.f - wx) * (1.f - wy) : 0.f;
            const float w10 = (vx1 & vy0) ? wa * wx * (1.f - wy) : 0.f;
            const float w01 = (vx0 & vy1) ? wa * (1.f - wx) * wy : 0.f;
            const float w11 = (vx1 & vy1) ? wa * wx * wy : 0.f;

            const int xc0 = min(max(x0, 0), Wl - 1);
            const int xc1 = min(max(x0 + 1, 0), Wl - 1);
            const int yc0 = min(max(y0, 0), Wl - 1);
            const int yc1 = min(max(y0 + 1, 0), Wl - 1);

            const int o00 = (s0 + yc0 * Wl + xc0) << 6;     // byte off, row 64B
            const int dx  = (xc1 - xc0) << 6;               // 0 or 64
            const int dy  = ((yc1 - yc0) * Wl) << 6;        // 0..6144

            int4 offs;
            offs.x = o00;           // corner 00 -> weight at rp+4
            offs.y = o00 + dx;      // corner 10 -> weight at rp+6
            offs.z = o00 + dy;      // corner 01 -> weight at rp+8
            offs.w = o00 + dy + dx; // corner 11 -> weight at rp+10
            float4 wab, wcd;
            wab.x = w00; wab.y = w00; wab.z = w10; wab.w = w10;
            wcd.x = w01; wcd.y = w01; wcd.z = w11; wcd.w = w11;

            int* rp = myrec + t * 96;       // pt = t*8 + p
            *(int4*)rp = offs;
            *(float4*)(rp + 4) = wab;
            *(float4*)(rp + 8) = wcd;
        }
    }
    __syncthreads();

    // ---- phase 2: corner-pair dwordx4 gathers (32 instrs/wave) ----
    const int c   = lane & 7;
    const int c4  = c & 3;              // 16B channel quad (8 channels)
    const int cr2 = c >> 2;             // corner of pair: A={00,10}, B={01,11}
    const unsigned c16 = (unsigned)(c4 * 16);
    const unsigned char* vp = (const unsigned char*)
        (v + ((size_t)(n * 8 + m) * SN) * 32);              // uniform base
    const int* grec = &pls[w][qi * 196];
    const int* gw   = grec + 4 + cr2 * 2;   // per-lane weight base

    // 8 channels per lane: acc0={ch0,1}, acc1={ch2,3}, acc2={ch4,5}, acc3={ch6,7}
    f32x2 acc0 = (f32x2)0.f, acc1 = (f32x2)0.f;
    f32x2 acc2 = (f32x2)0.f, acc3 = (f32x2)0.f;

#define ACC8(U, W) { f32x2 t; \
    t.x = bf_lo((U).x); t.y = bf_hi((U).x); acc0 += (W) * t; \
    t.x = bf_lo((U).y); t.y = bf_hi((U).y); acc1 += (W) * t; \
    t.x = bf_lo((U).z); t.y = bf_hi((U).z); acc2 += (W) * t; \
    t.x = bf_lo((U).w); t.y = bf_hi((U).w); acc3 += (W) * t; }

    #pragma unroll
    for (int g = 0; g < 4; g++) {
        const int4 o0 = *(const int4*)(grec + (g * 4 + 0) * 12);
        const int4 o1 = *(const int4*)(grec + (g * 4 + 1) * 12);
        const int4 o2 = *(const int4*)(grec + (g * 4 + 2) * 12);
        const int4 o3 = *(const int4*)(grec + (g * 4 + 3) * 12);

        // per point: corner cr2 (A) and corner 2+cr2 (B), 16B each
        const unsigned a0 = (unsigned)(cr2 ? o0.y : o0.x) + c16;
        const unsigned b0 = (unsigned)(cr2 ? o0.w : o0.z) + c16;
        const unsigned a1 = (unsigned)(cr2 ? o1.y : o1.x) + c16;
        const unsigned b1 = (unsigned)(cr2 ? o1.w : o1.z) + c16;
        const unsigned a2 = (unsigned)(cr2 ? o2.y : o2.x) + c16;
        const unsigned b2 = (unsigned)(cr2 ? o2.w : o2.z) + c16;
        const unsigned a3 = (unsigned)(cr2 ? o3.y : o3.x) + c16;
        const unsigned b3 = (unsigned)(cr2 ? o3.w : o3.z) + c16;

        const uint4 uA0 = *(const uint4*)(vp + a0);
        const uint4 uB0 = *(const uint4*)(vp + b0);
        const uint4 uA1 = *(const uint4*)(vp + a1);
        const uint4 uB1 = *(const uint4*)(vp + b1);
        const uint4 uA2 = *(const uint4*)(vp + a2);
        const uint4 uB2 = *(const uint4*)(vp + b2);
        const uint4 uA3 = *(const uint4*)(vp + a3);
        const uint4 uB3 = *(const uint4*)(vp + b3);

        const f32x2 wA0 = *(const f32x2*)(gw + (g * 4 + 0) * 12);
        const f32x2 wB0 = *(const f32x2*)(gw + (g * 4 + 0) * 12 + 4);
        const f32x2 wA1 = *(const f32x2*)(gw + (g * 4 + 1) * 12);
        const f32x2 wB1 = *(const f32x2*)(gw + (g * 4 + 1) * 12 + 4);
        const f32x2 wA2 = *(const f32x2*)(gw + (g * 4 + 2) * 12);
        const f32x2 wB2 = *(const f32x2*)(gw + (g * 4 + 2) * 12 + 4);
        const f32x2 wA3 = *(const f32x2*)(gw + (g * 4 + 3) * 12);
        const f32x2 wB3 = *(const f32x2*)(gw + (g * 4 + 3) * 12 + 4);

        ACC8(uA0, wA0) ACC8(uB0, wB0)
        ACC8(uA1, wA1) ACC8(uB1, wB1)
        ACC8(uA2, wA2) ACC8(uB2, wB2)
        ACC8(uA3, wA3) ACC8(uB3, wB3)
    }
#undef ACC8

    // combine corner halves: partner lane (lane ^ 4) holds the other 2 corners
    acc0.x += __shfl_xor(acc0.x, 4); acc0.y += __shfl_xor(acc0.y, 4);
    acc1.x += __shfl_xor(acc1.x, 4); acc1.y += __shfl_xor(acc1.y, 4);
    acc2.x += __shfl_xor(acc2.x, 4); acc2.y += __shfl_xor(acc2.y, 4);
    acc3.x += __shfl_xor(acc3.x, 4); acc3.y += __shfl_xor(acc3.y, 4);

    // lane writes 4 of its 8 channels: cr2=0 -> ch {0..3}, cr2=1 -> ch {4..7}
    const f32x2 wlo = cr2 ? acc2 : acc0;
    const f32x2 whi = cr2 ? acc3 : acc1;
    ushort4 o;
    o.x = f2bf(wlo.x); o.y = f2bf(wlo.y); o.z = f2bf(whi.x); o.w = f2bf(whi.y);
    *(ushort4*)(out + qb * 256 + m * 32 + c4 * 8 + cr2 * 4) = o;
}

// ---------------------------------------------------------------------------
extern "C" void kernel_launch(void* const* d_in, const int* in_sizes, int n_in,
                              void* d_out, int out_size, void* d_ws, size_t ws_size,
                              hipStream_t stream)
{
    const float* queries = (const float*)d_in[0];
    const float* geom    = (const float*)d_in[1];
    const float* src     = (const float*)d_in[2];
    const float* W_off   = (const float*)d_in[3];
    const float* b_off   = (const float*)d_in[4];
    const float* W_attn  = (const float*)d_in[5];
    const float* b_attn  = (const float*)d_in[6];
    const float* W_val   = (const float*)d_in[7];
    const float* b_val   = (const float*)d_in[8];
    const float* W_out   = (const float*)d_in[9];
    const float* b_out   = (const float*)d_in[10];
    float* out = (float*)d_out;

    ushortT* wsb = (ushortT*)d_ws;
    const size_t PADROW = (size_t)MPAD * 256;          // 6,291,456 elems
    ushortT* q_bf    = wsb;
    ushortT* srcmdv  = wsb + PADROW;                   // src_bf, later mdv_bf
    ushortT* v_bf    = wsb + 2 * PADROW;               // head-major v
    ushortT* wt_val  = wsb + 3 * PADROW;               // 256*256
    ushortT* wt_lo   = wt_val + 65536;                 // 384*256
    ushortT* wt_out  = wt_lo + 98304;                  // 256*256
    float* lo_ws = (float*)(wt_out + 65536);           // 24480*384 fp32
    // total ~75.8 MB

    dim3 blk(256);

    cast_all<<<dim3(7016), blk, 0, stream>>>(
        queries, src, W_val, W_attn, W_off, W_out,
        q_bf, srcmdv, wt_val, wt_lo, wt_out);

    // bx<2: v = src@W_val -> v_bf (bf16 head-major); bx>=2: lo -> lo_ws
    // (64-row tiles: 1920 WGs for occupancy)
    gemm_vlo<<<dim3(5, 384), blk, 0, stream>>>(
        q_bf, srcmdv, wt_val, wt_lo, b_val, b_attn, b_off, v_bf, lo_ws);

    sample_kernel<<<dim3((QN + 31) / 32, 8, NB), dim3(256), 0, stream>>>(
        lo_ws, geom, v_bf, srcmdv);

    // 64x64 tiles: 1536 WGs for occupancy
    gemm_out<<<dim3(4, 384), blk, 0, stream>>>(srcmdv, wt_out, b_out, out);
}